// Round 2
// baseline (306.005 us; speedup 1.0000x reference)
//
#include <hip/hip_runtime.h>

// B=4, S=2048, D=1024, H=16, HD=64. f32 in/out, fp16 MFMA, fp32 accumulate.
// R11 = R10 with raw asm s_barrier replaced by __builtin_amdgcn_s_barrier()
// (convergence-visible barrier, matches the verified 8-phase template).
// GEMMs: 256x128-tile, 8-wave, 4-phase/K-tile, triple-buffered LDS (144 KiB),
// counted vmcnt(6), setprio around MFMA clusters. prep/attn/post = R9.
#define B_  4
#define S_  2048
#define D_  1024
#define H_  16
#define HD_ 64
#define BH_ (B_*H_)
// Q pre-scale: 1/sqrt(64) * log2(e)  (softmax done in exp2 space)
#define QSCALE 0.18033688f

typedef _Float16 h16;
typedef _Float16 h4 __attribute__((ext_vector_type(4)));
typedef _Float16 h8 __attribute__((ext_vector_type(8)));
typedef float    f32x4 __attribute__((ext_vector_type(4)));

#define EXP2(x) __builtin_amdgcn_exp2f(x)   // v_exp_f32 (D = 2^S0)
#define BAR()   __builtin_amdgcn_s_barrier()

// async global->LDS, 16B/lane: lane i's 16B lands at ldst + i*16 (wave-
// uniform base). Swizzled staging: lane reads global chunk (row, cc^(row&7))
// so that LDS chunk (row, cc') holds global (row, cc'^(row&7)).
__device__ __forceinline__ void gload16(const h16* g, h16* l) {
  __builtin_amdgcn_global_load_lds(
      (const __attribute__((address_space(1))) unsigned int*)g,
      (__attribute__((address_space(3))) unsigned int*)l, 16, 0, 0);
}

// ---------------------------------------------------------------------------
// prep: [0,4) maskscan | [4,6) b_in conv | [6,4102) x conv | [4102,7174) w_in T
// ---------------------------------------------------------------------------
__global__ __launch_bounds__(256)
void prep_k(const float* __restrict__ x, const float* __restrict__ w_in,
            const float* __restrict__ b_in, const int* __restrict__ mask,
            h16* __restrict__ xc, h16* __restrict__ WinT,
            h16* __restrict__ binc, int* __restrict__ posmap,
            int* __restrict__ nvalid) {
  __shared__ __align__(16) char smem[2212];
  int blk = blockIdx.x;
  int t = threadIdx.x;
  if (blk < 4) {                      // mask prefix-scan, one block per batch
    int* partial = (int*)smem;
    int b = blk;
    const int* mb = mask + b * S_;
    int base = t * 8;
    int loc[8], cnt = 0;
#pragma unroll
    for (int j = 0; j < 8; j++) { loc[j] = cnt; cnt += (mb[base + j] != 0); }
    partial[t] = cnt;
    __syncthreads();
    for (int off = 1; off < 256; off <<= 1) {
      int v = (t >= off) ? partial[t - off] : 0;
      __syncthreads();
      partial[t] += v;
      __syncthreads();
    }
    int excl = (t == 0) ? 0 : partial[t - 1];
#pragma unroll
    for (int j = 0; j < 8; j++)
      posmap[b * S_ + base + j] = (mb[base + j] != 0) ? (excl + loc[j]) : -1;
    if (t == 255) nvalid[b] = partial[255];
  } else if (blk < 6) {               // b_in convert (3072 elems)
    int idx = ((blk - 4) * 256 + t) * 8;
    if (idx + 8 <= 3 * D_) {
      float4 f0 = *(const float4*)(b_in + idx);
      float4 f1 = *(const float4*)(b_in + idx + 4);
      h16 tmp[8] = {(h16)f0.x, (h16)f0.y, (h16)f0.z, (h16)f0.w,
                    (h16)f1.x, (h16)f1.y, (h16)f1.z, (h16)f1.w};
      *(h8*)(binc + idx) = *(h8*)tmp;
    }
  } else if (blk < 4102) {            // x convert (8.4M elems)
    int idx = ((blk - 6) * 256 + t) * 8;
    float4 f0 = *(const float4*)(x + idx);
    float4 f1 = *(const float4*)(x + idx + 4);
    h16 tmp[8] = {(h16)f0.x, (h16)f0.y, (h16)f0.z, (h16)f0.w,
                  (h16)f1.x, (h16)f1.y, (h16)f1.z, (h16)f1.w};
    *(h8*)(xc + idx) = *(h8*)tmp;
  } else {                            // w_in transpose (1024 x 3072 -> T)
    typedef h16 row33[33];
    row33* tile = (row33*)smem;
    int idx = blk - 4102;             // 96 x 32 tiles
    int bx = (idx % 96) * 32, by = (idx / 96) * 32;
    int tx = t & 31, ty = t >> 5;     // (32, 8)
    const int C = 3 * D_, R = D_;
#pragma unroll
    for (int i = 0; i < 32; i += 8)
      tile[ty + i][tx] = (h16)w_in[(size_t)(by + ty + i) * C + bx + tx];
    __syncthreads();
#pragma unroll
    for (int i = 0; i < 32; i += 8)
      WinT[(size_t)(bx + ty + i) * R + by + tx] = tile[tx][ty + i];
  }
}

// ---------------------------------------------------------------------------
// post: [0,1024) w_out transpose | [1024] b_out convert
// ---------------------------------------------------------------------------
__global__ __launch_bounds__(256)
void post_k(const float* __restrict__ w_out, const float* __restrict__ b_out,
            h16* __restrict__ WouT, h16* __restrict__ boutc) {
  __shared__ h16 tile[32][33];
  int blk = blockIdx.x;
  int t = threadIdx.x;
  if (blk < 1024) {                   // 32 x 32 tiles of (1024,1024)
    int bx = (blk % 32) * 32, by = (blk / 32) * 32;
    int tx = t & 31, ty = t >> 5;
#pragma unroll
    for (int i = 0; i < 32; i += 8)
      tile[ty + i][tx] = (h16)w_out[(size_t)(by + ty + i) * D_ + bx + tx];
    __syncthreads();
#pragma unroll
    for (int i = 0; i < 32; i += 8)
      WouT[(size_t)(bx + ty + i) * D_ + by + tx] = tile[tx][ty + i];
  } else {
    int idx = t * 4;
    if (idx < D_) {
      float4 f = *(const float4*)(b_out + idx);
      h16 tmp[4] = {(h16)f.x, (h16)f.y, (h16)f.z, (h16)f.w};
      *(h4*)(boutc + idx) = *(h4*)tmp;
    }
  }
}

// ---------------------------------------------------------------------------
// 256x128 MFMA GEMM, BK=64, 8 waves (4M x 2N), triple-buffered swizzled LDS,
// 4 phases per K-tile with counted vmcnt. A (M x K) rm, BT (N x K) rm.
// MODE 0: qkv -> Q (QSCALE,+bias) / compacted Kc,Vtc via posmap.
// MODE 1: out proj -> d_out f32 (+bias).
// ---------------------------------------------------------------------------
__device__ __forceinline__ void stage_rounds(const h16* __restrict__ G, h16* L,
                                             int rbase, int K, int kt,
                                             int w, int lane, int p0, int np,
                                             int wchunks) {
#pragma unroll
  for (int p = p0; p < p0 + np; ++p) {
    int c = w * wchunks + p * 64 + lane;
    int row = c >> 3;
    int cc = (c & 7) ^ (row & 7);
    gload16(&G[(size_t)(rbase + row) * K + kt + cc * 8],
            &L[(w * wchunks + p * 64) * 8]);
  }
}

template <int IO, int JO>
__device__ __forceinline__ void mfma8(f32x4 (&acc)[4][4], const h8 (&afr)[2][2],
                                      const h8 (&bfr)[4][2]) {
  __builtin_amdgcn_s_setprio(1);
#pragma unroll
  for (int i = 0; i < 2; ++i)
#pragma unroll
    for (int j = 0; j < 2; ++j)
#pragma unroll
      for (int k = 0; k < 2; ++k)
        acc[IO + i][JO + j] = __builtin_amdgcn_mfma_f32_16x16x32_f16(
            afr[i][k], bfr[JO + j][k], acc[IO + i][JO + j], 0, 0, 0);
  __builtin_amdgcn_s_setprio(0);
}

template <int MODE>
__global__ __launch_bounds__(512)
void gemm256_k(const h16* __restrict__ A, const h16* __restrict__ BT,
               const h16* __restrict__ bias, const int* __restrict__ posmap,
               void* __restrict__ out0v, h16* __restrict__ out1,
               h16* __restrict__ out2, int M, int N, int K) {
  const int tid  = threadIdx.x;
  const int lane = tid & 63;
  const int w    = tid >> 6;          // 0..7
  const int quad = lane >> 4;
  const int l16  = lane & 15;
  const int m0   = blockIdx.x * 256;
  const int n0   = blockIdx.y * 128;
  const int wm   = (w >> 1) * 64;     // 0,64,128,192
  const int wn   = (w & 1) * 64;      // 0,64
  const int sw   = l16 & 7;           // read-side swizzle key

  __shared__ alignas(16) h16 As[3][256 * 64];   // 96 KiB
  __shared__ alignas(16) h16 Bs[3][128 * 64];   // 48 KiB

  const f32x4 zero = {0.f, 0.f, 0.f, 0.f};
  f32x4 acc[4][4];
#pragma unroll
  for (int i = 0; i < 4; i++)
#pragma unroll
    for (int j = 0; j < 4; j++) acc[i][j] = zero;

  const int nt = K >> 6;              // 16

  // prologue: stage tiles 0,1 into buffers 0,1 (6 glds each, FIFO order)
#pragma unroll
  for (int tt = 0; tt < 2; ++tt) {
    stage_rounds(A,  As[tt], m0, K, tt * 64, w, lane, 0, 4, 256);
    stage_rounds(BT, Bs[tt], n0, K, tt * 64, w, lane, 0, 2, 128);
  }

  h8 afr[2][2];   // current m-half frags [m][kk]
  h8 bfr[4][2];   // all n frags [n][kk]

  for (int t = 0; t < nt; ++t) {
    const int cb = t % 3;             // compute buffer
    int sb = cb + 2; if (sb >= 3) sb -= 3;   // stage buffer = (t+2)%3
    const h16* Ab = As[cb];
    const h16* Bb = Bs[cb];
    const int ktn = (t + 2) * 64;
    const bool st = (t + 2) < nt;

    // wait tile t staged (6 younger glds for t+1 stay in flight), sync
    if (t + 1 < nt) asm volatile("s_waitcnt vmcnt(6)" ::: "memory");
    else            asm volatile("s_waitcnt vmcnt(0)" ::: "memory");
    BAR();

    // ---- P1: read A mh0 + B nh0; stage A rounds 0-1 of tile t+2 ----
#pragma unroll
    for (int i = 0; i < 2; ++i)
#pragma unroll
      for (int k = 0; k < 2; ++k)
        afr[i][k] = *(const h8*)(Ab + (wm + i * 16 + l16) * 64 +
                                 ((k * 4 + quad) ^ sw) * 8);
#pragma unroll
    for (int j = 0; j < 2; ++j)
#pragma unroll
      for (int k = 0; k < 2; ++k)
        bfr[j][k] = *(const h8*)(Bb + (wn + j * 16 + l16) * 64 +
                                 ((k * 4 + quad) ^ sw) * 8);
    if (st) stage_rounds(A, As[sb], m0, K, ktn, w, lane, 0, 2, 256);
    BAR();
    mfma8<0, 0>(acc, afr, bfr);
    BAR();

    // ---- P2: read B nh1; stage A rounds 2-3 ----
#pragma unroll
    for (int j = 2; j < 4; ++j)
#pragma unroll
      for (int k = 0; k < 2; ++k)
        bfr[j][k] = *(const h8*)(Bb + (wn + j * 16 + l16) * 64 +
                                 ((k * 4 + quad) ^ sw) * 8);
    if (st) stage_rounds(A, As[sb], m0, K, ktn, w, lane, 2, 2, 256);
    BAR();
    mfma8<0, 2>(acc, afr, bfr);
    BAR();

    // ---- P3: read A mh1; stage B rounds 0-1 ----
#pragma unroll
    for (int i = 0; i < 2; ++i)
#pragma unroll
      for (int k = 0; k < 2; ++k)
        afr[i][k] = *(const h8*)(Ab + (wm + (2 + i) * 16 + l16) * 64 +
                                 ((k * 4 + quad) ^ sw) * 8);
    if (st) stage_rounds(BT, Bs[sb], n0, K, ktn, w, lane, 0, 2, 128);
    BAR();
    mfma8<2, 0>(acc, afr, bfr);
    BAR();

    // ---- P4: pure MFMA (regs only) ----
    mfma8<2, 2>(acc, afr, bfr);
  }

  // epilogue
#pragma unroll
  for (int i = 0; i < 4; i++) {
#pragma unroll
    for (int j = 0; j < 4; j++) {
      int n = n0 + wn + j * 16 + l16;
      float bv = (float)bias[n];
#pragma unroll
      for (int r = 0; r < 4; r++) {
        int m = m0 + wm + i * 16 + quad * 4 + r;
        float v = acc[i][j][r] + bv;
        if (MODE == 0) {
          h16* q0 = (h16*)out0v;
          int which = n >> 10;          // 0=Q, 1=K, 2=V
          int h  = (n >> 6) & 15;
          int hd = n & 63;
          int b  = m >> 11;
          int s  = m & 2047;
          if (which == 0) {
            q0[(((size_t)(b * 16 + h)) * S_ + s) * HD_ + hd] = (h16)(v * QSCALE);
          } else {
            int pos = posmap[b * S_ + s];
            if (pos >= 0) {
              if (which == 1)  // compacted K: (bh, pos, hd)
                out1[(((size_t)(b * 16 + h)) * S_ + pos) * HD_ + hd] = (h16)v;
              else             // compacted V^T: (bh, hd, pos)
                out2[(((size_t)(b * 16 + h)) * HD_ + hd) * S_ + pos] = (h16)v;
            }
          }
        } else {
          ((float*)out0v)[(size_t)m * N + n] = v;
        }
      }
    }
  }
}

// ---------------------------------------------------------------------------
// Flash attention, transposed scores, 64-key tiles, swizzled glds staging.
// grid (S/64, B*H), block 256. S^T = K*Q^T; softmax in exp2 space (Q carries
// log2e); P^T per-wave LDS = PV A-layout.
// ---------------------------------------------------------------------------
__global__ __launch_bounds__(256)
void attn_k(const h16* __restrict__ Q, const h16* __restrict__ Kc,
            const h16* __restrict__ Vtc, const int* __restrict__ nvalid,
            h16* __restrict__ out) {
  const int tid  = threadIdx.x;
  const int lane = tid & 63;
  const int w    = tid >> 6;
  const int quad = lane >> 4;
  const int l16  = lane & 15;
  const int bh   = blockIdx.y;
  const int b    = bh >> 4, h = bh & 15;
  const int q0   = blockIdx.x * 64 + w * 16;
  const int nv   = nvalid[b];
  const int sw   = l16 & 7;

  const h16* Qh = Q   + (size_t)bh * S_ * HD_;
  const h16* Kh = Kc  + (size_t)bh * S_ * HD_;
  const h16* Vh = Vtc + (size_t)bh * HD_ * S_;

  __shared__ alignas(16) h16 Ks[64 * 64];      // [key][hd], swizzled chunks
  __shared__ alignas(16) h16 Vs[64 * 64];      // [hd][key], swizzled chunks
  __shared__ alignas(16) h16 Pb[4][16 * 72];   // per-wave P^T, [q][key]

  h8 bq[2];
#pragma unroll
  for (int ks = 0; ks < 2; ks++)
    bq[ks] = *(const h8*)(&Qh[(size_t)(q0 + l16) * 64 + ks * 32 + quad * 8]);

  const f32x4 zero = {0.f, 0.f, 0.f, 0.f};
  f32x4 oacc[4];
#pragma unroll
  for (int j = 0; j < 4; j++) oacc[j] = zero;
  float mst = -1e30f, lst = 0.f;   // per-lane state for q = q0 + l16

  for (int kb = 0; kb < nv; kb += 64) {
    __syncthreads();
    // stage K (64x64) and V^T (64x64): 512 chunks each, 2 glds/wave each
#pragma unroll
    for (int p = 0; p < 2; p++) {
      int c   = w * 128 + p * 64 + lane;
      int row = c >> 3;
      int cc  = (c & 7) ^ (row & 7);
      gload16(&Kh[(size_t)(kb + row) * 64 + cc * 8],
              &Ks[(w * 128 + p * 64) * 8]);
      gload16(&Vh[(size_t)row * S_ + kb + cc * 8],
              &Vs[(w * 128 + p * 64) * 8]);
    }
    __syncthreads();

    // S^T: st[kh][r] = S[key = kh*16 + quad*4 + r][q = q0 + l16]
    f32x4 st[4];
#pragma unroll
    for (int kh = 0; kh < 4; kh++) {
      h8 ak0 = *(const h8*)(&Ks[(kh * 16 + l16) * 64 + (quad ^ sw) * 8]);
      h8 ak1 = *(const h8*)(&Ks[(kh * 16 + l16) * 64 + ((quad + 4) ^ sw) * 8]);
      f32x4 s = zero;
      s = __builtin_amdgcn_mfma_f32_16x16x32_f16(ak0, bq[0], s, 0, 0, 0);
      s = __builtin_amdgcn_mfma_f32_16x16x32_f16(ak1, bq[1], s, 0, 0, 0);
      st[kh] = s;
    }
    if (kb + 64 > nv) {  // wave-uniform tail mask
#pragma unroll
      for (int kh = 0; kh < 4; kh++)
#pragma unroll
        for (int r = 0; r < 4; r++)
          if (kb + kh * 16 + quad * 4 + r >= nv) st[kh][r] = -1e30f;
    }

    float mx = -1e30f;
#pragma unroll
    for (int kh = 0; kh < 4; kh++)
#pragma unroll
      for (int r = 0; r < 4; r++) mx = fmaxf(mx, st[kh][r]);
    mx = fmaxf(mx, __shfl_xor(mx, 16, 64));
    mx = fmaxf(mx, __shfl_xor(mx, 32, 64));
    float mnew = fmaxf(mst, mx);
    float alpha = EXP2(mst - mnew);         // exp2 space (Q carries log2e)
    float p[4][4], rs = 0.f;
#pragma unroll
    for (int kh = 0; kh < 4; kh++)
#pragma unroll
      for (int r = 0; r < 4; r++) {
        p[kh][r] = EXP2(st[kh][r] - mnew);
        rs += p[kh][r];
      }
    rs += __shfl_xor(rs, 16, 64);
    rs += __shfl_xor(rs, 32, 64);
    lst = lst * alpha + rs;
    mst = mnew;

    float al[4];
#pragma unroll
    for (int r = 0; r < 4; r++) al[r] = __shfl(alpha, quad * 4 + r, 64);
#pragma unroll
    for (int j = 0; j < 4; j++)
#pragma unroll
      for (int r = 0; r < 4; r++) oacc[j][r] *= al[r];

    // P^T -> per-wave LDS [q][key] (stride 72): PV A-layout
    h16* pb = Pb[w];
#pragma unroll
    for (int kh = 0; kh < 4; kh++) {
      h4 pk = {(h16)p[kh][0], (h16)p[kh][1], (h16)p[kh][2], (h16)p[kh][3]};
      *(h4*)(&pb[l16 * 72 + kh * 16 + quad * 4]) = pk;
    }
    h8 pa0 = *(const h8*)(&pb[l16 * 72 + quad * 8]);
    h8 pa1 = *(const h8*)(&pb[l16 * 72 + 32 + quad * 8]);

    // PV: O(16q x 64hd) += P(16q x 64k) * V(64k x 64hd)
#pragma unroll
    for (int j = 0; j < 4; j++) {
      h8 bv0 = *(const h8*)(&Vs[(j * 16 + l16) * 64 + (quad ^ sw) * 8]);
      h8 bv1 = *(const h8*)(&Vs[(j * 16 + l16) * 64 + ((quad + 4) ^ sw) * 8]);
      oacc[j] = __builtin_amdgcn_mfma_f32_16x16x32_f16(pa0, bv0, oacc[j], 0, 0, 0);
      oacc[j] = __builtin_amdgcn_mfma_f32_16x16x32_f16(pa1, bv1, oacc[j], 0, 0, 0);
    }
  }

  float ls[4];
#pragma unroll
  for (int r = 0; r < 4; r++) ls[r] = __shfl(lst, quad * 4 + r, 64);
#pragma unroll
  for (int j = 0; j < 4; j++)
#pragma unroll
    for (int r = 0; r < 4; r++) {
      int row = q0 + quad * 4 + r;
      float v = oacc[j][r] / ls[r];
      out[((size_t)(b * S_ + row)) * D_ + h * 64 + j * 16 + l16] = (h16)v;
    }
}

// ---------------------------------------------------------------------------
// ws (64 MiB, h16): Qb[0,NT) Kc[NT,2NT) Vtc[2NT,3NT) {xc|AOb}[3NT,4NT).
// WouT aliases Qb, boutc aliases Vtc (both written post-attn by post_k).
// d_out scratch (dead before gemm<1>): WinT[0,3.15M) binc@3.4M posmap@24MB.
// Order: prep -> gemm<0> -> attn -> post -> gemm<1>   (5 launches)
// ---------------------------------------------------------------------------
extern "C" void kernel_launch(void* const* d_in, const int* in_sizes, int n_in,
                              void* d_out, int out_size, void* d_ws,
                              size_t ws_size, hipStream_t stream) {
  const float* x     = (const float*)d_in[0];
  const float* w_in  = (const float*)d_in[1];
  const float* b_in  = (const float*)d_in[2];
  const float* w_out = (const float*)d_in[3];
  const float* b_out = (const float*)d_in[4];
  const int*   mask  = (const int*)d_in[5];

  const size_t NT = (size_t)BH_ * S_ * HD_;    // 8,388,608 elems
  h16* ws    = (h16*)d_ws;
  h16* Qb    = ws;
  h16* Kcb   = ws + NT;
  h16* Vtcb  = ws + 2 * NT;
  h16* xc    = ws + 3 * NT;
  h16* AOb   = ws + 3 * NT;
  h16* WouT  = Qb;
  h16* boutc = Vtcb;
  h16* WinT  = (h16*)d_out;
  h16* binc  = (h16*)d_out + 3400704;
  int* posmap = (int*)((char*)d_out + 24u * 1024 * 1024);
  int* nvalid = posmap + B_ * S_;

  prep_k<<<7174, 256, 0, stream>>>(x, w_in, b_in, mask, xc, WinT, binc,
                                   posmap, nvalid);

  gemm256_k<0><<<dim3((B_ * S_) / 256, (3 * D_) / 128), 512, 0, stream>>>(
      xc, WinT, binc, posmap, Qb, Kcb, Vtcb, B_ * S_, 3 * D_, D_);

  attn_k<<<dim3(S_ / 64, BH_), 256, 0, stream>>>(Qb, Kcb, Vtcb, nvalid, AOb);

  post_k<<<1025, 256, 0, stream>>>(w_out, b_out, WouT, boutc);

  gemm256_k<1><<<dim3((B_ * S_) / 256, D_ / 128), 512, 0, stream>>>(
      AOb, WouT, boutc, nullptr, d_out, nullptr, nullptr, B_ * S_, D_, D_);
}